// Round 4
// baseline (1388.394 us; speedup 1.0000x reference)
//
#include <hip/hip_runtime.h>

typedef __bf16 bf16x8 __attribute__((ext_vector_type(8)));
typedef float  f32x4  __attribute__((ext_vector_type(4)));

__device__ __forceinline__ float b2f(unsigned short u) {
    union { unsigned int i; float f; } v; v.i = ((unsigned int)u) << 16; return v.f;
}
__device__ __forceinline__ unsigned short f2b(float f) {
    union { float f; unsigned int i; } v; v.f = f;
    unsigned int u = v.i;
    return (unsigned short)((u + 0x7fffu + ((u >> 16) & 1u)) >> 16);
}

// ---------------- tap table build ----------------
__global__ void table_init(int* __restrict__ tab, int n)
{
    int idx = blockIdx.x * blockDim.x + threadIdx.x;
    if (idx >= n * 27) return;
    tab[idx] = ((idx % 27) == 13) ? (idx / 27) : -1;
}

__global__ void table_fill(int* __restrict__ tab, const int* __restrict__ map, int M, int n)
{
    int tid = blockIdx.x * blockDim.x + threadIdx.x;
    if (tid >= 26 * M) return;
    int j = tid / M, q = tid - j * M;
    int om = map[(26 + j) * M + q];
    if (om < n) {
        int k = (j < 13) ? j : j + 1;
        tab[om * 27 + k] = map[j * M + q];
    }
}

// ---------------- weight pack: W[j][k][cout] f32 -> B-fragment order bf16 ----------------
__global__ void pack_w(const float* __restrict__ W, unsigned short* __restrict__ P,
                       int total, int log2Cout, int log2KC)
{
    int tid = blockIdx.x * blockDim.x + threadIdx.x;
    if (tid >= total) return;
    int jj   = tid & 7;
    int cout = (tid >> 3) & ((1 << log2Cout) - 1);
    int rest = tid >> (3 + log2Cout);
    int quad = rest & 3;
    int kj   = rest >> 2;
    int kc   = kj & ((1 << log2KC) - 1);
    int j    = kj >> log2KC;
    int Cin  = (1 << log2KC) * 32;
    int Cout = 1 << log2Cout;
    P[tid] = f2b(W[((size_t)j * Cin + kc * 32 + quad * 8 + jj) * Cout + cout]);
}

__global__ void cast_bf16(const float* __restrict__ X, unsigned short* __restrict__ Y, int nElem)
{
    int tid = blockIdx.x * blockDim.x + threadIdx.x;
    if (tid < nElem) Y[tid] = f2b(X[tid]);
}

// ---------------- MFMA output-centric sparse conv, 64 rows/block ----------------
// 256 threads = 4 waves. Wave wv owns Cout tiles [wv*T, wv*T+T). Each wave runs all
// 4 row-tiles against its B fragments -> B loads amortized 4x, 4*T independent acc chains.
template<int T, bool OUTBF16>
__global__ __launch_bounds__(256) void conv_mfma(
    const unsigned short* __restrict__ Xb, const unsigned short* __restrict__ P,
    const int* __restrict__ tab, void* __restrict__ OutV, int n, int Cin, int KC)
{
    const int Cout = 64 * T;
    __shared__ int tps[64 * 27];
    __shared__ int vld[27];
    const int t = threadIdx.x, lane = t & 63, wv = t >> 6;
    const int m = lane & 15, quad = lane >> 4;
    const int r0 = blockIdx.x * 64;
    int rows = n - r0; if (rows > 64) rows = 64;

    for (int e = t; e < 64 * 27; e += 256)
        tps[e] = (e < rows * 27) ? tab[(size_t)r0 * 27 + e] : -1;
    __syncthreads();
    if (t < 27) {
        int v = 0;
        for (int r = 0; r < 64; r++)
            if (tps[r * 27 + t] >= 0) v |= 1 << (r >> 4);
        vld[t] = v;
    }
    __syncthreads();

    f32x4 acc[4][T];
    #pragma unroll
    for (int rt = 0; rt < 4; rt++)
        #pragma unroll
        for (int c = 0; c < T; c++) acc[rt][c] = f32x4{0.f, 0.f, 0.f, 0.f};

    for (int j = 0; j < 27; j++) {
        const int v = vld[j];
        if (!v) continue;
        int inr[4];
        #pragma unroll
        for (int rt = 0; rt < 4; rt++) inr[rt] = tps[(rt * 16 + m) * 27 + j];
        for (int kc = 0; kc < KC; kc++) {
            const unsigned short* bp = P + ((size_t)((j * KC + kc) * 4 + quad) * Cout + wv * (T * 16)) * 8;
            bf16x8 b[T];
            #pragma unroll
            for (int c = 0; c < T; c++)
                b[c] = *reinterpret_cast<const bf16x8*>(bp + (c * 16 + m) * 8);
            #pragma unroll
            for (int rt = 0; rt < 4; rt++) {
                if (!((v >> rt) & 1)) continue;
                bf16x8 a{};
                if (inr[rt] >= 0)
                    a = *reinterpret_cast<const bf16x8*>(Xb + (size_t)inr[rt] * Cin + kc * 32 + quad * 8);
                #pragma unroll
                for (int c = 0; c < T; c++)
                    acc[rt][c] = __builtin_amdgcn_mfma_f32_16x16x32_bf16(a, b[c], acc[rt][c], 0, 0, 0);
            }
        }
    }

    #pragma unroll
    for (int rt = 0; rt < 4; rt++)
        #pragma unroll
        for (int c = 0; c < T; c++) {
            int cout = (wv * T + c) * 16 + m;
            #pragma unroll
            for (int reg = 0; reg < 4; reg++) {
                int r = rt * 16 + quad * 4 + reg;
                if (r < rows) {
                    size_t off = (size_t)(r0 + r) * Cout + cout;
                    if (OUTBF16) ((unsigned short*)OutV)[off] = f2b(acc[rt][c][reg]);
                    else         ((float*)OutV)[off] = acc[rt][c][reg];
                }
            }
        }
}

// ---------------- MFMA transpose conv: 8 children per row, A held in regs ----------------
template<int KC, int T>
__global__ __launch_bounds__(256) void tconv_mfma(
    const unsigned short* __restrict__ Xb, const unsigned short* __restrict__ P,
    unsigned short* __restrict__ Out, int n)
{
    const int Cin = KC * 32, Cout = 64 * T;
    const int t = threadIdx.x, lane = t & 63, wv = t >> 6;
    const int m = lane & 15, quad = lane >> 4;
    const int r0 = blockIdx.x * 16;
    int rows = n - r0; if (rows > 16) rows = 16;

    bf16x8 a[KC];
    #pragma unroll
    for (int kc = 0; kc < KC; kc++) {
        a[kc] = bf16x8{};
        if (m < rows)
            a[kc] = *reinterpret_cast<const bf16x8*>(Xb + (size_t)(r0 + m) * Cin + kc * 32 + quad * 8);
    }

    for (int o = 0; o < 8; o++) {
        f32x4 acc[T];
        #pragma unroll
        for (int c = 0; c < T; c++) acc[c] = f32x4{0.f, 0.f, 0.f, 0.f};
        #pragma unroll
        for (int kc = 0; kc < KC; kc++) {
            const unsigned short* bp = P + ((size_t)((o * KC + kc) * 4 + quad) * Cout + wv * (T * 16)) * 8;
            #pragma unroll
            for (int c = 0; c < T; c++) {
                bf16x8 b = *reinterpret_cast<const bf16x8*>(bp + (c * 16 + m) * 8);
                acc[c] = __builtin_amdgcn_mfma_f32_16x16x32_bf16(a[kc], b, acc[c], 0, 0, 0);
            }
        }
        #pragma unroll
        for (int c = 0; c < T; c++) {
            int cout = (wv * T + c) * 16 + m;
            #pragma unroll
            for (int reg = 0; reg < 4; reg++) {
                int r = quad * 4 + reg;
                if (r < rows)
                    Out[((size_t)o * n + r0 + r) * Cout + cout] = f2b(acc[c][reg]);
            }
        }
    }
}

// ---------------- misc ----------------
__global__ void scatter_add_f32(float* __restrict__ dst, const float* __restrict__ src,
                                const int* __restrict__ idx, long total, int C)
{
    long tid = (long)blockIdx.x * blockDim.x + threadIdx.x;
    if (tid >= total) return;
    long r = tid / C;
    int  c = (int)(tid - r * C);
    dst[(long)idx[r] * C + c] += src[tid];
}

__global__ void scatter_add_b16(float* __restrict__ dst, const unsigned short* __restrict__ src,
                                const int* __restrict__ idx, long total, int C)
{
    long tid = (long)blockIdx.x * blockDim.x + threadIdx.x;
    if (tid >= total) return;
    long r = tid / C;
    int  c = (int)(tid - r * C);
    dst[(long)idx[r] * C + c] += b2f(src[tid]);
}

template<bool BF16>
__global__ void bn_stats_k(const void* __restrict__ Xv, float* __restrict__ stats,
                           int n, int C, int rowsPerBlock)
{
    const int t = threadIdx.x;
    const int c = t & (C - 1);
    const int sub = t / C;
    const int nsub = 256 / C;
    int r0 = blockIdx.x * rowsPerBlock + sub;
    int r1 = blockIdx.x * rowsPerBlock + rowsPerBlock;
    if (r1 > n) r1 = n;
    float s = 0.f, ss = 0.f;
    for (int r = r0; r < r1; r += nsub) {
        float v = BF16 ? b2f(((const unsigned short*)Xv)[(long)r * C + c])
                       : ((const float*)Xv)[(long)r * C + c];
        s += v; ss += v * v;
    }
    __shared__ float bs[256];
    __shared__ float bq[256];
    bs[t] = s; bq[t] = ss;
    __syncthreads();
    if (sub == 0) {
        for (int k = 1; k < nsub; k++) { s += bs[k * C + c]; ss += bq[k * C + c]; }
        atomicAdd(&stats[c], s);
        atomicAdd(&stats[C + c], ss);
    }
}

template<bool BF16>
__global__ void bn_apply_k(void* __restrict__ Xv, const float* __restrict__ stats,
                           const float* __restrict__ gb, long total, int C, float invn)
{
    long tid = (long)blockIdx.x * blockDim.x + threadIdx.x;
    if (tid >= total) return;
    int c = (int)(tid & (C - 1));
    float mu  = stats[c] * invn;
    float var = stats[C + c] * invn - mu * mu;
    float sc  = gb[c] * rsqrtf(var + 1e-5f);
    float x   = BF16 ? b2f(((unsigned short*)Xv)[tid]) : ((float*)Xv)[tid];
    float v   = (x - mu) * sc + gb[C + c];
    v = (v > 0.f) ? v : expm1f(v);
    if (BF16) ((unsigned short*)Xv)[tid] = f2b(v);
    else      ((float*)Xv)[tid] = v;
}

extern "C" void kernel_launch(void* const* d_in, const int* in_sizes, int n_in,
                              void* d_out, int out_size, void* d_ws, size_t ws_size,
                              hipStream_t stream)
{
    const float* feats0  = (const float*)d_in[0];
    const float* feats1  = (const float*)d_in[1];
    const float* feats2  = (const float*)d_in[2];
    const float* w_out0  = (const float*)d_in[3];
    const float* w_out1  = (const float*)d_in[4];
    const float* w_out2  = (const float*)d_in[5];
    const float* wt2     = (const float*)d_in[6];
    const float* wu2     = (const float*)d_in[7];
    const float* wt1     = (const float*)d_in[8];
    const float* wu1     = (const float*)d_in[9];
    const float* bn_out0 = (const float*)d_in[10];
    const float* bn_out1 = (const float*)d_in[11];
    const float* bn_out2 = (const float*)d_in[12];
    const float* bn_up2a = (const float*)d_in[13];
    const float* bn_up2b = (const float*)d_in[14];
    const float* bn_up1a = (const float*)d_in[15];
    const float* bn_up1b = (const float*)d_in[16];
    const int* m_c2 = (const int*)d_in[19];
    const int* m_g2 = (const int*)d_in[20];
    const int* m_u1 = (const int*)d_in[21];
    const int* m_g1 = (const int*)d_in[22];
    const int* m_u0 = (const int*)d_in[23];
    const int* lat1 = (const int*)d_in[24];
    const int* up1  = (const int*)d_in[25];
    const int* lat0 = (const int*)d_in[26];
    const int* up0  = (const int*)d_in[27];

    const int N0  = in_sizes[0] / 64;
    const int N1  = in_sizes[1] / 128;
    const int N2  = in_sizes[2] / 256;
    const int U1  = in_sizes[17] / 128;
    const int U0  = in_sizes[18] / 64;
    const int G2n = in_sizes[25];        // 8*N2
    const int G1n = in_sizes[27];        // 8*U1
    const int Mc2 = in_sizes[19] / 52;
    const int Mg2 = in_sizes[20] / 52;
    const int Mu1 = in_sizes[21] / 52;
    const int Mg1 = in_sizes[22] / 52;
    const int Mu0 = in_sizes[23] / 52;

    float* out0 = (float*)d_out;
    float* out1 = out0 + (size_t)U0 * 128;
    float* out2 = out1 + (size_t)U1 * 128;

    // ---- workspace (256B-aligned bump allocator) ----
    char* wp = (char*)d_ws;
    auto alloc = [&](size_t bytes) -> char* {
        char* r = wp; wp += (bytes + 255) & ~(size_t)255; return r;
    };
    float*          x0   = (float*)alloc((size_t)U0 * 64 * 4);   // tab_g1 aliases (built before x0 written)
    unsigned short* t1   = (unsigned short*)alloc((size_t)G1n * 64 * 2);  // tab_u0 aliases t1|t1c (both dead)
    unsigned short* t1c  = (unsigned short*)alloc((size_t)G1n * 64 * 2);
    unsigned short* t2   = (unsigned short*)alloc((size_t)G2n * 128 * 2);
    unsigned short* t2c  = (unsigned short*)alloc((size_t)G2n * 128 * 2);
    float*          x1   = (float*)alloc((size_t)U1 * 128 * 4);
    unsigned short* x1b  = (unsigned short*)alloc((size_t)U1 * 128 * 2);
    unsigned short* x0b  = (unsigned short*)alloc((size_t)U0 * 64 * 2);
    unsigned short* f2bb = (unsigned short*)alloc((size_t)N2 * 256 * 2);
    unsigned short* pc2  = (unsigned short*)alloc((size_t)27 * 256 * 128 * 2);
    unsigned short* pt2  = (unsigned short*)alloc((size_t)8  * 256 * 128 * 2);
    unsigned short* pg2  = (unsigned short*)alloc((size_t)27 * 128 * 128 * 2);
    unsigned short* pu1  = (unsigned short*)alloc((size_t)27 * 128 * 128 * 2);
    unsigned short* pt1  = (unsigned short*)alloc((size_t)8  * 128 * 64  * 2);
    unsigned short* pg1  = (unsigned short*)alloc((size_t)27 * 64  * 64  * 2);
    unsigned short* pu0  = (unsigned short*)alloc((size_t)27 * 64  * 128 * 2);
    int maxSmall = (U1 > G2n) ? U1 : G2n;
    int*   smallTab = (int*)alloc((size_t)maxSmall * 27 * 4);
    float* stats    = (float*)alloc(1024);
    int* tab_g1 = (int*)x0;   // G1n*27*4  <= U0*64*4 since U0 >= G1n
    int* tab_u0 = (int*)t1;   // U0*27*4   <= 2*G1n*64*2 region (t1+t1c)

    auto packW = [&](const float* W, unsigned short* P, int taps, int l2co, int l2kc) {
        int total = taps * ((1 << l2kc) * 32) * (1 << l2co);
        pack_w<<<dim3((total + 255) / 256), dim3(256), 0, stream>>>(W, P, total, l2co, l2kc);
    };
    auto cast = [&](const float* X, unsigned short* Y, long nElem) {
        cast_bf16<<<dim3((int)((nElem + 255) / 256)), dim3(256), 0, stream>>>(X, Y, (int)nElem);
    };
    auto buildTab = [&](int* tab, const int* map, int M, int n) {
        table_init<<<dim3((n * 27 + 255) / 256), dim3(256), 0, stream>>>(tab, n);
        table_fill<<<dim3((26 * M + 255) / 256), dim3(256), 0, stream>>>(tab, map, M, n);
    };
    auto conv = [&](const unsigned short* Xb, const unsigned short* P, const int* tab,
                    void* Out, int n, int Cin, int Cout, bool outbf16) {
        int blocks = (n + 63) / 64, KC = Cin / 32;
        if (Cout == 128) {
            if (outbf16) conv_mfma<2, true ><<<dim3(blocks), dim3(256), 0, stream>>>(Xb, P, tab, Out, n, Cin, KC);
            else         conv_mfma<2, false><<<dim3(blocks), dim3(256), 0, stream>>>(Xb, P, tab, Out, n, Cin, KC);
        } else {
            if (outbf16) conv_mfma<1, true ><<<dim3(blocks), dim3(256), 0, stream>>>(Xb, P, tab, Out, n, Cin, KC);
            else         conv_mfma<1, false><<<dim3(blocks), dim3(256), 0, stream>>>(Xb, P, tab, Out, n, Cin, KC);
        }
    };
    auto bnelu = [&](void* X, const float* gb, int n, int C, bool bf16) {
        hipMemsetAsync(stats, 0, 2 * C * sizeof(float), stream);
        const int rpb = 512;
        long total = (long)n * C;
        if (bf16) {
            bn_stats_k<true ><<<dim3((n + rpb - 1) / rpb), dim3(256), 0, stream>>>(X, stats, n, C, rpb);
            bn_apply_k<true ><<<dim3((int)((total + 255) / 256)), dim3(256), 0, stream>>>(X, stats, gb, total, C, 1.0f / n);
        } else {
            bn_stats_k<false><<<dim3((n + rpb - 1) / rpb), dim3(256), 0, stream>>>(X, stats, n, C, rpb);
            bn_apply_k<false><<<dim3((int)((total + 255) / 256)), dim3(256), 0, stream>>>(X, stats, gb, total, C, 1.0f / n);
        }
    };

    // ---- weight packs + input cast ----
    cast(feats2, f2bb, (long)N2 * 256);
    packW(w_out2, pc2, 27, 7, 3);
    packW(wt2,    pt2,  8, 7, 3);
    packW(wu2,    pg2, 27, 7, 2);
    packW(w_out1, pu1, 27, 7, 2);
    packW(wt1,    pt1,  8, 6, 2);
    packW(wu1,    pg1, 27, 6, 1);
    packW(w_out0, pu0, 27, 7, 1);

    // ---- level 2 ----
    buildTab(smallTab, m_c2, Mc2, N2);
    conv(f2bb, pc2, smallTab, out2, N2, 256, 128, false);
    bnelu(out2, bn_out2, N2, 128, false);
    tconv_mfma<8, 2><<<dim3((N2 + 15) / 16), dim3(256), 0, stream>>>(f2bb, pt2, t2, N2);
    bnelu(t2, bn_up2a, G2n, 128, true);
    buildTab(smallTab, m_g2, Mg2, G2n);
    conv(t2, pg2, smallTab, t2c, G2n, 128, 128, true);
    bnelu(t2c, bn_up2b, G2n, 128, true);

    // ---- level 1 ----
    hipMemsetAsync(x1, 0, (size_t)U1 * 128 * sizeof(float), stream);
    {
        long tot = (long)N1 * 128;
        scatter_add_f32<<<dim3((int)((tot + 255) / 256)), dim3(256), 0, stream>>>(x1, feats1, lat1, tot, 128);
        tot = (long)G2n * 128;
        scatter_add_b16<<<dim3((int)((tot + 255) / 256)), dim3(256), 0, stream>>>(x1, t2c, up1, tot, 128);
    }
    cast(x1, x1b, (long)U1 * 128);
    buildTab(smallTab, m_u1, Mu1, U1);
    conv(x1b, pu1, smallTab, out1, U1, 128, 128, false);
    bnelu(out1, bn_out1, U1, 128, false);
    tconv_mfma<4, 1><<<dim3((U1 + 15) / 16), dim3(256), 0, stream>>>(x1b, pt1, t1, U1);
    bnelu(t1, bn_up1a, G1n, 64, true);
    buildTab(tab_g1, m_g1, Mg1, G1n);
    conv(t1, pg1, tab_g1, t1c, G1n, 64, 64, true);
    bnelu(t1c, bn_up1b, G1n, 64, true);

    // ---- level 0 ----
    hipMemsetAsync(x0, 0, (size_t)U0 * 64 * sizeof(float), stream);
    {
        long tot = (long)N0 * 64;
        scatter_add_f32<<<dim3((int)((tot + 255) / 256)), dim3(256), 0, stream>>>(x0, feats0, lat0, tot, 64);
        tot = (long)G1n * 64;
        scatter_add_b16<<<dim3((int)((tot + 255) / 256)), dim3(256), 0, stream>>>(x0, t1c, up0, tot, 64);
    }
    buildTab(tab_u0, m_u0, Mu0, U0);
    cast(x0, x0b, (long)U0 * 64);
    conv(x0b, pu0, tab_u0, out0, U0, 64, 128, false);
    bnelu(out0, bn_out0, U0, 128, false);
}

// Round 5
// 1363.177 us; speedup vs baseline: 1.0185x; 1.0185x over previous
//
#include <hip/hip_runtime.h>

typedef __bf16 bf16x8 __attribute__((ext_vector_type(8)));
typedef float  f32x4  __attribute__((ext_vector_type(4)));

__device__ __forceinline__ float b2f(unsigned short u) {
    union { unsigned int i; float f; } v; v.i = ((unsigned int)u) << 16; return v.f;
}
__device__ __forceinline__ unsigned short f2b(float f) {
    union { float f; unsigned int i; } v; v.f = f;
    unsigned int u = v.i;
    return (unsigned short)((u + 0x7fffu + ((u >> 16) & 1u)) >> 16);
}

// ---------------- tap table build ----------------
// tab[r*27+j] = input row for output r, tap j; sentinel = n (zero row), center = r.
__global__ void table_init(int* __restrict__ tab, int n)
{
    int idx = blockIdx.x * blockDim.x + threadIdx.x;
    if (idx >= n * 27) return;
    tab[idx] = ((idx % 27) == 13) ? (idx / 27) : n;
}

__global__ void table_fill(int* __restrict__ tab, const int* __restrict__ map, int M, int n)
{
    int tid = blockIdx.x * blockDim.x + threadIdx.x;
    if (tid >= 26 * M) return;
    int j = tid / M, q = tid - j * M;
    int om = map[(26 + j) * M + q];
    if (om < n) {
        int k = (j < 13) ? j : j + 1;
        tab[om * 27 + k] = map[j * M + q];
    }
}

// ---------------- weight pack: W[j][k][cout] f32 -> B-fragment order bf16 ----------------
__global__ void pack_w(const float* __restrict__ W, unsigned short* __restrict__ P,
                       int total, int log2Cout, int log2KC)
{
    int tid = blockIdx.x * blockDim.x + threadIdx.x;
    if (tid >= total) return;
    int jj   = tid & 7;
    int cout = (tid >> 3) & ((1 << log2Cout) - 1);
    int rest = tid >> (3 + log2Cout);
    int quad = rest & 3;
    int kj   = rest >> 2;
    int kc   = kj & ((1 << log2KC) - 1);
    int j    = kj >> log2KC;
    int Cin  = (1 << log2KC) * 32;
    int Cout = 1 << log2Cout;
    P[tid] = f2b(W[((size_t)j * Cin + kc * 32 + quad * 8 + jj) * Cout + cout]);
}

__global__ void cast_bf16(const float* __restrict__ X, unsigned short* __restrict__ Y, int nElem)
{
    int tid = blockIdx.x * blockDim.x + threadIdx.x;
    if (tid < nElem) Y[tid] = f2b(X[tid]);
}

// ---------------- one pipeline step: 2 k-chunks (64 channels) of tap j ----------------
// Branch-free: invalid rows point at the zero row (index n). SSA registers per call
// let the scheduler hoist the next step's loads above this step's MFMAs.
template<int T>
__device__ __forceinline__ void conv_step(
    const unsigned short* __restrict__ Xb, const unsigned short* __restrict__ P,
    const int* __restrict__ tps_g, int RPB2, int j, int kc0,
    int m, int quad, int coutBase, int Cin, int Cout, int KC, f32x4 (&acc)[4][T])
{
    bf16x8 a[4][2], b[T][2];
    #pragma unroll
    for (int u = 0; u < 2; u++) {
        int kc = kc0 + u;
        #pragma unroll
        for (int rt = 0; rt < 4; rt++) {
            int row = tps_g[j * RPB2 + rt * 16 + m];
            a[rt][u] = *reinterpret_cast<const bf16x8*>(Xb + (size_t)row * Cin + kc * 32 + quad * 8);
        }
        #pragma unroll
        for (int c = 0; c < T; c++)
            b[c][u] = *reinterpret_cast<const bf16x8*>(
                P + (((size_t)(j * KC + kc) * 4 + quad) * Cout + coutBase + c * 16 + m) * 8);
    }
    #pragma unroll
    for (int u = 0; u < 2; u++)
        #pragma unroll
        for (int rt = 0; rt < 4; rt++)
            #pragma unroll
            for (int c = 0; c < T; c++)
                acc[rt][c] = __builtin_amdgcn_mfma_f32_16x16x32_bf16(a[rt][u], b[c][u], acc[rt][c], 0, 0, 0);
}

// ---------------- MFMA output-centric sparse conv ----------------
// 256 threads = 4 waves. RG row-groups of 64 rows; WPG=4/RG waves per group each owning
// T cout-tiles (Cout = WPG*T*16). Compacted valid-tap list; 2-step software pipeline.
template<int KC, int T, int RG, bool OUTBF16>
__global__ __launch_bounds__(256) void conv_mfma(
    const unsigned short* __restrict__ Xb, const unsigned short* __restrict__ P,
    const int* __restrict__ tab, void* __restrict__ OutV, int n)
{
    const int Cin = KC * 32, WPG = 4 / RG, Cout = WPG * T * 16, RPB2 = RG * 64;
    __shared__ int tps[27 * RPB2];
    __shared__ int vjs[27];
    __shared__ int vmask[27];
    __shared__ int nvS;

    const int t = threadIdx.x, lane = t & 63, wv = t >> 6;
    const int m = lane & 15, quad = lane >> 4;
    const int g = wv / WPG, coutBase = (wv % WPG) * T * 16;
    const long r0 = (long)blockIdx.x * RPB2;
    int rows = (int)(n - r0); if (rows > RPB2) rows = RPB2;

    if (t < 27) vmask[t] = 0;
    __syncthreads();
    for (int e = t; e < 27 * RPB2; e += 256) {
        int r = e / 27, j = e - r * 27;
        int v = (r < rows) ? tab[(r0 + r) * 27 + j] : n;
        tps[j * RPB2 + r] = v;
        if (v != n) vmask[j] = 1;
    }
    __syncthreads();
    if (t == 0) {
        int c = 0;
        for (int j = 0; j < 27; j++) if (vmask[j]) vjs[c++] = j;
        nvS = c;
    }
    __syncthreads();
    const int nv = nvS;

    f32x4 acc[4][T];
    #pragma unroll
    for (int rt = 0; rt < 4; rt++)
        #pragma unroll
        for (int c = 0; c < T; c++) acc[rt][c] = f32x4{0.f, 0.f, 0.f, 0.f};

    const int* tps_g = tps + g * 64;
    const int spj_sh = (KC == 2) ? 0 : (KC == 4) ? 1 : 2;   // log2(KC/2)
    const int kcmask = (KC / 2) - 1;
    int tot = nv << spj_sh;
    int s = 0;
    for (; s + 2 <= tot; s += 2) {
        conv_step<T>(Xb, P, tps_g, RPB2, vjs[s >> spj_sh], (s & kcmask) * 2,
                     m, quad, coutBase, Cin, Cout, KC, acc);
        conv_step<T>(Xb, P, tps_g, RPB2, vjs[(s + 1) >> spj_sh], ((s + 1) & kcmask) * 2,
                     m, quad, coutBase, Cin, Cout, KC, acc);
    }
    if (s < tot)
        conv_step<T>(Xb, P, tps_g, RPB2, vjs[s >> spj_sh], (s & kcmask) * 2,
                     m, quad, coutBase, Cin, Cout, KC, acc);

    #pragma unroll
    for (int rt = 0; rt < 4; rt++)
        #pragma unroll
        for (int c = 0; c < T; c++) {
            int cout = coutBase + c * 16 + m;
            #pragma unroll
            for (int reg = 0; reg < 4; reg++) {
                long r = r0 + g * 64 + rt * 16 + quad * 4 + reg;
                if (r < n) {
                    size_t off = (size_t)r * Cout + cout;
                    if (OUTBF16) ((unsigned short*)OutV)[off] = f2b(acc[rt][c][reg]);
                    else         ((float*)OutV)[off] = acc[rt][c][reg];
                }
            }
        }
}

// ---------------- MFMA transpose conv: 8 children per row, A held in regs ----------------
template<int KC, int T>
__global__ __launch_bounds__(256) void tconv_mfma(
    const unsigned short* __restrict__ Xb, const unsigned short* __restrict__ P,
    unsigned short* __restrict__ Out, int n)
{
    const int Cin = KC * 32, Cout = 64 * T;
    const int t = threadIdx.x, lane = t & 63, wv = t >> 6;
    const int m = lane & 15, quad = lane >> 4;
    const int r0 = blockIdx.x * 16;
    int rows = n - r0; if (rows > 16) rows = 16;

    bf16x8 a[KC];
    #pragma unroll
    for (int kc = 0; kc < KC; kc++) {
        a[kc] = bf16x8{};
        if (m < rows)
            a[kc] = *reinterpret_cast<const bf16x8*>(Xb + (size_t)(r0 + m) * Cin + kc * 32 + quad * 8);
    }

    for (int o = 0; o < 8; o++) {
        f32x4 acc[T];
        #pragma unroll
        for (int c = 0; c < T; c++) acc[c] = f32x4{0.f, 0.f, 0.f, 0.f};
        #pragma unroll
        for (int kc = 0; kc < KC; kc++) {
            const unsigned short* bp = P + ((size_t)((o * KC + kc) * 4 + quad) * Cout + wv * (T * 16)) * 8;
            #pragma unroll
            for (int c = 0; c < T; c++) {
                bf16x8 b = *reinterpret_cast<const bf16x8*>(bp + (c * 16 + m) * 8);
                acc[c] = __builtin_amdgcn_mfma_f32_16x16x32_bf16(a[kc], b, acc[c], 0, 0, 0);
            }
        }
        #pragma unroll
        for (int c = 0; c < T; c++) {
            int cout = (wv * T + c) * 16 + m;
            #pragma unroll
            for (int reg = 0; reg < 4; reg++) {
                int r = quad * 4 + reg;
                if (r < rows)
                    Out[((size_t)o * n + r0 + r) * Cout + cout] = f2b(acc[c][reg]);
            }
        }
    }
}

// ---------------- misc ----------------
__global__ void scatter_add_f32(float* __restrict__ dst, const float* __restrict__ src,
                                const int* __restrict__ idx, long total, int C)
{
    long tid = (long)blockIdx.x * blockDim.x + threadIdx.x;
    if (tid >= total) return;
    long r = tid / C;
    int  c = (int)(tid - r * C);
    dst[(long)idx[r] * C + c] += src[tid];
}

__global__ void scatter_add_b16(float* __restrict__ dst, const unsigned short* __restrict__ src,
                                const int* __restrict__ idx, long total, int C)
{
    long tid = (long)blockIdx.x * blockDim.x + threadIdx.x;
    if (tid >= total) return;
    long r = tid / C;
    int  c = (int)(tid - r * C);
    dst[(long)idx[r] * C + c] += b2f(src[tid]);
}

template<bool BF16>
__global__ void bn_stats_k(const void* __restrict__ Xv, float* __restrict__ stats,
                           int n, int C, int rowsPerBlock)
{
    const int t = threadIdx.x;
    const int c = t & (C - 1);
    const int sub = t / C;
    const int nsub = 256 / C;
    int r0 = blockIdx.x * rowsPerBlock + sub;
    int r1 = blockIdx.x * rowsPerBlock + rowsPerBlock;
    if (r1 > n) r1 = n;
    float s = 0.f, ss = 0.f;
    for (int r = r0; r < r1; r += nsub) {
        float v = BF16 ? b2f(((const unsigned short*)Xv)[(long)r * C + c])
                       : ((const float*)Xv)[(long)r * C + c];
        s += v; ss += v * v;
    }
    __shared__ float bs[256];
    __shared__ float bq[256];
    bs[t] = s; bq[t] = ss;
    __syncthreads();
    if (sub == 0) {
        for (int k = 1; k < nsub; k++) { s += bs[k * C + c]; ss += bq[k * C + c]; }
        atomicAdd(&stats[c], s);
        atomicAdd(&stats[C + c], ss);
    }
}

template<bool BF16>
__global__ void bn_apply_k(void* __restrict__ Xv, const float* __restrict__ stats,
                           const float* __restrict__ gb, long total, int C, float invn)
{
    long tid = (long)blockIdx.x * blockDim.x + threadIdx.x;
    if (tid >= total) return;
    int c = (int)(tid & (C - 1));
    float mu  = stats[c] * invn;
    float var = stats[C + c] * invn - mu * mu;
    float sc  = gb[c] * rsqrtf(var + 1e-5f);
    float x   = BF16 ? b2f(((unsigned short*)Xv)[tid]) : ((float*)Xv)[tid];
    float v   = (x - mu) * sc + gb[C + c];
    v = (v > 0.f) ? v : expm1f(v);
    if (BF16) ((unsigned short*)Xv)[tid] = f2b(v);
    else      ((float*)Xv)[tid] = v;
}

extern "C" void kernel_launch(void* const* d_in, const int* in_sizes, int n_in,
                              void* d_out, int out_size, void* d_ws, size_t ws_size,
                              hipStream_t stream)
{
    const float* feats0  = (const float*)d_in[0];
    const float* feats1  = (const float*)d_in[1];
    const float* feats2  = (const float*)d_in[2];
    const float* w_out0  = (const float*)d_in[3];
    const float* w_out1  = (const float*)d_in[4];
    const float* w_out2  = (const float*)d_in[5];
    const float* wt2     = (const float*)d_in[6];
    const float* wu2     = (const float*)d_in[7];
    const float* wt1     = (const float*)d_in[8];
    const float* wu1     = (const float*)d_in[9];
    const float* bn_out0 = (const float*)d_in[10];
    const float* bn_out1 = (const float*)d_in[11];
    const float* bn_out2 = (const float*)d_in[12];
    const float* bn_up2a = (const float*)d_in[13];
    const float* bn_up2b = (const float*)d_in[14];
    const float* bn_up1a = (const float*)d_in[15];
    const float* bn_up1b = (const float*)d_in[16];
    const int* m_c2 = (const int*)d_in[19];
    const int* m_g2 = (const int*)d_in[20];
    const int* m_u1 = (const int*)d_in[21];
    const int* m_g1 = (const int*)d_in[22];
    const int* m_u0 = (const int*)d_in[23];
    const int* lat1 = (const int*)d_in[24];
    const int* up1  = (const int*)d_in[25];
    const int* lat0 = (const int*)d_in[26];
    const int* up0  = (const int*)d_in[27];

    const int N0  = in_sizes[0] / 64;
    const int N1  = in_sizes[1] / 128;
    const int N2  = in_sizes[2] / 256;
    const int U1  = in_sizes[17] / 128;
    const int U0  = in_sizes[18] / 64;
    const int G2n = in_sizes[25];        // 8*N2
    const int G1n = in_sizes[27];        // 8*U1
    const int Mc2 = in_sizes[19] / 52;
    const int Mg2 = in_sizes[20] / 52;
    const int Mu1 = in_sizes[21] / 52;
    const int Mg1 = in_sizes[22] / 52;
    const int Mu0 = in_sizes[23] / 52;

    float* out0 = (float*)d_out;
    float* out1 = out0 + (size_t)U0 * 128;
    float* out2 = out1 + (size_t)U1 * 128;

    // ---- workspace (256B-aligned bump allocator); bf16 tensors get +1 zero row ----
    char* wp = (char*)d_ws;
    auto alloc = [&](size_t bytes) -> char* {
        char* r = wp; wp += (bytes + 255) & ~(size_t)255; return r;
    };
    float*          x0   = (float*)alloc((size_t)U0 * 64 * 4);              // tab_g1 aliases
    unsigned short* t1   = (unsigned short*)alloc((size_t)(G1n + 1) * 64 * 2);  // tab_u0 aliases t1|t1c
    unsigned short* t1c  = (unsigned short*)alloc((size_t)G1n * 64 * 2);
    unsigned short* t2   = (unsigned short*)alloc((size_t)(G2n + 1) * 128 * 2);
    unsigned short* t2c  = (unsigned short*)alloc((size_t)G2n * 128 * 2);
    float*          x1   = (float*)alloc((size_t)U1 * 128 * 4);
    unsigned short* x1b  = (unsigned short*)alloc((size_t)(U1 + 1) * 128 * 2);
    unsigned short* x0b  = (unsigned short*)alloc((size_t)(U0 + 1) * 64 * 2);
    unsigned short* f2bb = (unsigned short*)alloc((size_t)(N2 + 1) * 256 * 2);
    unsigned short* pc2  = (unsigned short*)alloc((size_t)27 * 256 * 128 * 2);
    unsigned short* pt2  = (unsigned short*)alloc((size_t)8  * 256 * 128 * 2);
    unsigned short* pg2  = (unsigned short*)alloc((size_t)27 * 128 * 128 * 2);
    unsigned short* pu1  = (unsigned short*)alloc((size_t)27 * 128 * 128 * 2);
    unsigned short* pt1  = (unsigned short*)alloc((size_t)8  * 128 * 64  * 2);
    unsigned short* pg1  = (unsigned short*)alloc((size_t)27 * 64  * 64  * 2);
    unsigned short* pu0  = (unsigned short*)alloc((size_t)27 * 64  * 128 * 2);
    int maxSmall = (U1 > G2n) ? U1 : G2n;
    int*   smallTab = (int*)alloc((size_t)maxSmall * 27 * 4);
    float* stats    = (float*)alloc(1024);
    int* tab_g1 = (int*)x0;   // G1n*27*4  <= U0*64*4
    int* tab_u0 = (int*)t1;   // U0*27*4   < (t1|t1c) region; t1 zero row sits past it

    // zero rows for the sentinel index (ws is re-poisoned every launch)
    hipMemsetAsync(f2bb + (size_t)N2 * 256, 0, 256 * 2, stream);
    hipMemsetAsync(t2   + (size_t)G2n * 128, 0, 128 * 2, stream);
    hipMemsetAsync(x1b  + (size_t)U1 * 128, 0, 128 * 2, stream);
    hipMemsetAsync(t1   + (size_t)G1n * 64, 0, 64 * 2, stream);
    hipMemsetAsync(x0b  + (size_t)U0 * 64, 0, 64 * 2, stream);

    auto packW = [&](const float* W, unsigned short* P, int taps, int l2co, int l2kc) {
        int total = taps * ((1 << l2kc) * 32) * (1 << l2co);
        pack_w<<<dim3((total + 255) / 256), dim3(256), 0, stream>>>(W, P, total, l2co, l2kc);
    };
    auto cast = [&](const float* X, unsigned short* Y, long nElem) {
        cast_bf16<<<dim3((int)((nElem + 255) / 256)), dim3(256), 0, stream>>>(X, Y, (int)nElem);
    };
    auto buildTab = [&](int* tab, const int* map, int M, int n) {
        table_init<<<dim3((n * 27 + 255) / 256), dim3(256), 0, stream>>>(tab, n);
        table_fill<<<dim3((26 * M + 255) / 256), dim3(256), 0, stream>>>(tab, map, M, n);
    };
    auto bnelu = [&](void* X, const float* gb, int n, int C, bool bf16) {
        hipMemsetAsync(stats, 0, 2 * C * sizeof(float), stream);
        const int rpb = 512;
        long total = (long)n * C;
        if (bf16) {
            bn_stats_k<true ><<<dim3((n + rpb - 1) / rpb), dim3(256), 0, stream>>>(X, stats, n, C, rpb);
            bn_apply_k<true ><<<dim3((int)((total + 255) / 256)), dim3(256), 0, stream>>>(X, stats, gb, total, C, 1.0f / n);
        } else {
            bn_stats_k<false><<<dim3((n + rpb - 1) / rpb), dim3(256), 0, stream>>>(X, stats, n, C, rpb);
            bn_apply_k<false><<<dim3((int)((total + 255) / 256)), dim3(256), 0, stream>>>(X, stats, gb, total, C, 1.0f / n);
        }
    };

    // ---- weight packs + input cast ----
    cast(feats2, f2bb, (long)N2 * 256);
    packW(w_out2, pc2, 27, 7, 3);
    packW(wt2,    pt2,  8, 7, 3);
    packW(wu2,    pg2, 27, 7, 2);
    packW(w_out1, pu1, 27, 7, 2);
    packW(wt1,    pt1,  8, 6, 2);
    packW(wu1,    pg1, 27, 6, 1);
    packW(w_out0, pu0, 27, 7, 1);

    // ---- level 2 ----
    buildTab(smallTab, m_c2, Mc2, N2);
    conv_mfma<8, 2, 1, false><<<dim3((N2 + 63) / 64), dim3(256), 0, stream>>>(f2bb, pc2, smallTab, out2, N2);
    bnelu(out2, bn_out2, N2, 128, false);
    tconv_mfma<8, 2><<<dim3((N2 + 15) / 16), dim3(256), 0, stream>>>(f2bb, pt2, t2, N2);
    bnelu(t2, bn_up2a, G2n, 128, true);
    buildTab(smallTab, m_g2, Mg2, G2n);
    conv_mfma<4, 2, 1, true><<<dim3((G2n + 63) / 64), dim3(256), 0, stream>>>(t2, pg2, smallTab, t2c, G2n);
    bnelu(t2c, bn_up2b, G2n, 128, true);

    // ---- level 1 ----
    hipMemsetAsync(x1, 0, (size_t)U1 * 128 * sizeof(float), stream);
    {
        long tot = (long)N1 * 128;
        scatter_add_f32<<<dim3((int)((tot + 255) / 256)), dim3(256), 0, stream>>>(x1, feats1, lat1, tot, 128);
        tot = (long)G2n * 128;
        scatter_add_b16<<<dim3((int)((tot + 255) / 256)), dim3(256), 0, stream>>>(x1, t2c, up1, tot, 128);
    }
    cast(x1, x1b, (long)U1 * 128);
    buildTab(smallTab, m_u1, Mu1, U1);
    conv_mfma<4, 2, 1, false><<<dim3((U1 + 63) / 64), dim3(256), 0, stream>>>(x1b, pu1, smallTab, out1, U1);
    bnelu(out1, bn_out1, U1, 128, false);
    tconv_mfma<4, 1><<<dim3((U1 + 15) / 16), dim3(256), 0, stream>>>(x1b, pt1, t1, U1);
    bnelu(t1, bn_up1a, G1n, 64, true);
    buildTab(tab_g1, m_g1, Mg1, G1n);
    conv_mfma<2, 2, 2, true><<<dim3((G1n + 127) / 128), dim3(256), 0, stream>>>(t1, pg1, tab_g1, t1c, G1n);
    bnelu(t1c, bn_up1b, G1n, 64, true);

    // ---- level 0 ----
    hipMemsetAsync(x0, 0, (size_t)U0 * 64 * sizeof(float), stream);
    {
        long tot = (long)N0 * 64;
        scatter_add_f32<<<dim3((int)((tot + 255) / 256)), dim3(256), 0, stream>>>(x0, feats0, lat0, tot, 64);
        tot = (long)G1n * 64;
        scatter_add_b16<<<dim3((int)((tot + 255) / 256)), dim3(256), 0, stream>>>(x0, t1c, up0, tot, 64);
    }
    buildTab(tab_u0, m_u0, Mu0, U0);
    cast(x0, x0b, (long)U0 * 64);
    conv_mfma<2, 2, 1, false><<<dim3((U0 + 63) / 64), dim3(256), 0, stream>>>(x0b, pu0, tab_u0, out0, U0);
    bnelu(out0, bn_out0, U0, 128, false);
}